// Round 4
// baseline (763.079 us; speedup 1.0000x reference)
//
#include <hip/hip_runtime.h>
#include <cstdint>
#include <cstddef>

#define D_MODEL 1024
#define DIN     2048
#define NSTATE  16
#define LSEQ    2048
#define NBATCH  2
#define NROWS   (NBATCH*LSEQ)   // 4096
#define NCOL    (DIN + 128)     // 2176 = sp(2048) | B(16) | C(16) | pad(96)
#define CCH     32              // scan chunks
#define TC      (LSEQ/CCH)      // 64 steps per chunk
#define LOG2E   1.4426950408889634f

typedef float  f32x4  __attribute__((ext_vector_type(4)));
typedef short  bf16x8 __attribute__((ext_vector_type(8)));
typedef unsigned short us8 __attribute__((ext_vector_type(8)));

__device__ __forceinline__ unsigned short f2bf(float f) {
  union { float f; unsigned u; } c; c.f = f;
  unsigned x = c.u + 0x7fffu + ((c.u >> 16) & 1u);   // RNE
  return (unsigned short)(x >> 16);
}
__device__ __forceinline__ float bf2f(unsigned short u) {
  union { unsigned u; float f; } c; c.u = (unsigned)u << 16; return c.f;
}
__device__ __forceinline__ float sigmoidf_(float x) { return 1.f / (1.f + __expf(-x)); }
__device__ __forceinline__ float softplusf_(float x) {
  return fmaxf(x, 0.f) + log1pf(__expf(-fabsf(x)));
}

// async global->LDS, 16B per lane; lds dest = wave-uniform base + lane*16
__device__ __forceinline__ void gll16(const void* g, void* l) {
  __builtin_amdgcn_global_load_lds(
      (const __attribute__((address_space(1))) void*)g,
      (__attribute__((address_space(3))) void*)l, 16, 0, 0);
}

// ---------------- layernorm (one row per block, D=1024); optional pos-add fuse --
__global__ __launch_bounds__(256) void ln_kernel(const float* __restrict__ Xin,
    const float* __restrict__ pos, const float* __restrict__ w,
    const float* __restrict__ b, unsigned short* __restrict__ outB,
    float* __restrict__ outF, float* __restrict__ Xsum) {
  int row = blockIdx.x, t = threadIdx.x;
  float4 v = *(const float4*)(Xin + (size_t)row * D_MODEL + t * 4);
  if (pos) {
    const float4 p = *(const float4*)(pos + (size_t)(row & (LSEQ - 1)) * D_MODEL + t * 4);
    v.x += p.x; v.y += p.y; v.z += p.z; v.w += p.w;
    if (Xsum) *(float4*)(Xsum + (size_t)row * D_MODEL + t * 4) = v;
  }
  float s  = v.x + v.y + v.z + v.w;
  float s2 = v.x * v.x + v.y * v.y + v.z * v.z + v.w * v.w;
#pragma unroll
  for (int o = 1; o < 64; o <<= 1) { s += __shfl_xor(s, o, 64); s2 += __shfl_xor(s2, o, 64); }
  __shared__ float ps[8];
  int wv = t >> 6;
  if ((t & 63) == 0) { ps[wv] = s; ps[wv + 4] = s2; }
  __syncthreads();
  s  = ps[0] + ps[1] + ps[2] + ps[3];
  s2 = ps[4] + ps[5] + ps[6] + ps[7];
  float mean = s * (1.f / D_MODEL);
  float var  = s2 * (1.f / D_MODEL) - mean * mean;
  float rs   = rsqrtf(var + 1e-5f);
  const float4 wv4 = *(const float4*)(w + t * 4);
  const float4 bv4 = *(const float4*)(b + t * 4);
  float o0 = (v.x - mean) * rs * wv4.x + bv4.x;
  float o1 = (v.y - mean) * rs * wv4.y + bv4.y;
  float o2 = (v.z - mean) * rs * wv4.z + bv4.z;
  float o3 = (v.w - mean) * rs * wv4.w + bv4.w;
  if (outB) {
    ushort4 o; o.x = f2bf(o0); o.y = f2bf(o1); o.z = f2bf(o2); o.w = f2bf(o3);
    *(ushort4*)(outB + (size_t)row * D_MODEL + t * 4) = o;
  } else {
    float4 o; o.x = o0; o.y = o1; o.z = o2; o.w = o3;
    *(float4*)(outF + (size_t)row * D_MODEL + t * 4) = o;
  }
}

// ---------------- transpose + fp32->bf16: out[n][k] = in[k][n] ----------------
__global__ __launch_bounds__(256) void tcvt_kernel(const float* __restrict__ in,
    unsigned short* __restrict__ out, int K_, int N_) {
  __shared__ float tile[64][68];
  int n0 = blockIdx.x * 64, k0 = blockIdx.y * 64;
  int t = threadIdx.x;
  int r = t >> 4, cc = (t & 15) * 4;
#pragma unroll
  for (int j = 0; j < 4; j++) {
    const float4 v = *(const float4*)(in + (size_t)(k0 + r + j * 16) * N_ + n0 + cc);
    tile[r + j * 16][cc + 0] = v.x; tile[r + j * 16][cc + 1] = v.y;
    tile[r + j * 16][cc + 2] = v.z; tile[r + j * 16][cc + 3] = v.w;
  }
  __syncthreads();
  int nr = t >> 2, kc = (t & 3) * 16;
  unsigned u[8];
#pragma unroll
  for (int i = 0; i < 8; i++) {
    unsigned lo = f2bf(tile[kc + 2 * i][nr]);
    unsigned hi = f2bf(tile[kc + 2 * i + 1][nr]);
    u[i] = lo | (hi << 16);
  }
  uint4* dst = (uint4*)(out + (size_t)(n0 + nr) * K_ + k0 + kc);
  uint4 w0; w0.x = u[0]; w0.y = u[1]; w0.z = u[2]; w0.w = u[3];
  uint4 w1; w1.x = u[4]; w1.y = u[5]; w1.z = u[6]; w1.w = u[7];
  dst[0] = w0; dst[1] = w1;
}

// ---- merged prep: WB/WC^T rows 2048..2079, zero pad rows 2080..2175, bias2 ----
__global__ __launch_bounds__(256) void wprep_kernel(const float* __restrict__ WB,
    const float* __restrict__ WC, const float* __restrict__ b_dt,
    unsigned short* __restrict__ Wt, float* __restrict__ bias2) {
  int id = blockIdx.x * 256 + threadIdx.x;
  if (id < 65536) {                                     // 32 x 2048 transpose fill
    int k = id & (DIN - 1);
    int n2 = id >> 11;
    float v = (n2 < NSTATE) ? WB[(size_t)k * NSTATE + n2]
                            : WC[(size_t)k * NSTATE + (n2 - NSTATE)];
    Wt[(size_t)(DIN + n2) * DIN + k] = f2bf(v);
  } else if (id < 90112) {                              // zero 96x2048 bf16, x8 vec
    int z = id - 65536;
    uint4 zz; zz.x = zz.y = zz.z = zz.w = 0u;
    *(uint4*)(Wt + (size_t)2080 * DIN + (size_t)z * 8) = zz;
  } else if (id < 90112 + NCOL) {                       // bias2
    int i = id - 90112;
    bias2[i] = (i < DIN) ? b_dt[i] : 0.f;
  }
}

// ---------------- bf16 MFMA GEMM, depth-3 pipelined ----------------
// out = A[M][K] @ Bt[N][K]^T + bias (+res). 128x128 tile, BK=32, 4 waves x (4x4)
// 16x16x32 frags. 4 LDS buffers, counted vmcnt(8) (T3/T4-minimum), XCD swizzle.
template <bool HAS_RES, bool WRITE_F32, bool WRITE_BF>
__global__ __launch_bounds__(256) void gemm_kernel(
    const unsigned short* __restrict__ A, const unsigned short* __restrict__ Bt,
    const float* __restrict__ bias, const float* res,
    float* outF, unsigned short* __restrict__ outB,
    int M, int N, int K, int spCols) {
  __shared__ unsigned short sA[4][128 * 32];
  __shared__ unsigned short sB[4][128 * 32];
  const int t = threadIdx.x;
  const int lane = t & 63, wave = t >> 6;
  const int wr = wave >> 1, wc = wave & 1;

  // XCD-chunked bijective swizzle (m204): contiguous M-row chunks per XCD.
  const int gx = gridDim.x;
  const int orig = blockIdx.y * gx + blockIdx.x;
  const int nwg = gx * gridDim.y;
  const int q = nwg >> 3, r = nwg & 7;
  const int xcd = orig & 7, pp = orig >> 3;
  const int wgid = (xcd < r) ? (xcd * (q + 1) + pp)
                             : (r * (q + 1) + (xcd - r) * q + pp);
  const int mt = wgid / gx, nt = wgid - mt * gx;
  const int m0 = mt * 128, n0 = nt * 128;

  const int ar = t >> 2, ac = (t & 3) * 8;             // staging: 16B/lane, linear
  const int wseg = wave * 16 * 32;                     // wave-uniform LDS base (elems)
  const int lr = lane & 15, lk = (lane >> 4) * 8;

  f32x4 acc[4][4];
#pragma unroll
  for (int m = 0; m < 4; m++)
#pragma unroll
    for (int n = 0; n < 4; n++) acc[m][n] = (f32x4)0.f;

  auto STAGE = [&](int bi, int kk) {
    gll16(A  + (size_t)(m0 + ar) * K + kk + ac,      &sA[bi][wseg]);
    gll16(A  + (size_t)(m0 + 64 + ar) * K + kk + ac, &sA[bi][64 * 32 + wseg]);
    gll16(Bt + (size_t)(n0 + ar) * K + kk + ac,      &sB[bi][wseg]);
    gll16(Bt + (size_t)(n0 + 64 + ar) * K + kk + ac, &sB[bi][64 * 32 + wseg]);
  };
  auto COMPUTE = [&](int bi) {
    bf16x8 af[4], bg[4];
#pragma unroll
    for (int m = 0; m < 4; m++)
      af[m] = *(const bf16x8*)(&sA[bi][(wr * 64 + m * 16 + lr) * 32 + lk]);
#pragma unroll
    for (int n = 0; n < 4; n++)
      bg[n] = *(const bf16x8*)(&sB[bi][(wc * 64 + n * 16 + lr) * 32 + lk]);
#pragma unroll
    for (int m = 0; m < 4; m++)
#pragma unroll
      for (int n = 0; n < 4; n++)
        acc[m][n] = __builtin_amdgcn_mfma_f32_16x16x32_bf16(af[m], bg[n], acc[m][n], 0, 0, 0);
  };

  const int NT = K >> 5;                                // >= 32 for all our shapes
  STAGE(0, 0); STAGE(1, 32); STAGE(2, 64);
  int tt = 0;
  for (; tt < NT - 3; ++tt) {
    asm volatile("s_waitcnt vmcnt(8)" ::: "memory");    // oldest tile's 4 loads done
    __builtin_amdgcn_s_barrier();                       // all waves' loads done
    STAGE((tt + 3) & 3, (tt + 3) << 5);                 // prefetch depth-3
    COMPUTE(tt & 3);
  }
  asm volatile("s_waitcnt vmcnt(8)" ::: "memory");      // tail: NT-3
  __builtin_amdgcn_s_barrier();
  COMPUTE(tt & 3); ++tt;
  asm volatile("s_waitcnt vmcnt(4)" ::: "memory");      // NT-2
  __builtin_amdgcn_s_barrier();
  COMPUTE(tt & 3); ++tt;
  asm volatile("s_waitcnt vmcnt(0)" ::: "memory");      // NT-1
  __builtin_amdgcn_s_barrier();
  COMPUTE(tt & 3);

  const int lq = lane >> 4;
#pragma unroll
  for (int m = 0; m < 4; m++) {
    int row = m0 + wr * 64 + m * 16 + lq * 4;
#pragma unroll
    for (int n = 0; n < 4; n++) {
      int col = n0 + wc * 64 + n * 16 + lr;
      float bv = bias[col];
      bool sp = col < spCols;
#pragma unroll
      for (int j = 0; j < 4; j++) {
        size_t idx = (size_t)(row + j) * N + col;
        float v = acc[m][n][j] + bv;
        if (HAS_RES) v += res[idx];
        if (sp) v = softplusf_(v);
        if (WRITE_F32) outF[idx] = v;
        if (WRITE_BF) outB[idx] = f2bf(v);
      }
    }
  }
}

// ---------------- chunked selective scan (bf16 inputs) ----------------
// Thread owns one channel d and all 16 states in registers. grid (DIN/256, B, CCH).
// DTBCb: [B*L][NCOL] bf16, cols [0,2048)=softplus(dt), [2048,2064)=B, [2064,2080)=C.
__global__ __launch_bounds__(256) void scan1_kernel(
    const unsigned short* __restrict__ DTBCb, const unsigned short* __restrict__ Hbf,
    const float* __restrict__ A_log, float* __restrict__ Hc, float* __restrict__ Pc) {
  const int d = blockIdx.x * 256 + threadIdx.x;
  const int b = blockIdx.y, c = blockIdx.z;
  float a2[16], h[16];
#pragma unroll
  for (int n = 0; n < 16; n++) {
    a2[n] = -__expf(A_log[(size_t)d * NSTATE + n]) * LOG2E;
    h[n] = 0.f;
  }
  __shared__ float sBC[TC][32];                         // B | C per step
  {
    int tt0 = threadIdx.x >> 2, cc = (threadIdx.x & 3) * 8;
    const size_t row = (size_t)(b * LSEQ + c * TC + tt0);
    us8 v = *(const us8*)(DTBCb + row * NCOL + DIN + cc);
#pragma unroll
    for (int j = 0; j < 8; j++) sBC[tt0][cc + j] = bf2f(v[j]);
  }
  __syncthreads();
  float S = 0.f;
  const size_t base = (size_t)(b * LSEQ + c * TC);
  for (int tt = 0; tt < TC; ++tt) {
    float sp = bf2f(DTBCb[(base + tt) * NCOL + d]);
    float x  = bf2f(Hbf[(base + tt) * DIN + d]);
    S += sp;
    float sx = sp * x;
#pragma unroll
    for (int n = 0; n < 16; n++)
      h[n] = fmaf(h[n], exp2f(sp * a2[n]), sx * sBC[tt][n]);
  }
  const size_t chain = ((size_t)c * (NBATCH * DIN) + (size_t)b * DIN + d) * 16;
#pragma unroll
  for (int n = 0; n < 16; n++) {
    Hc[chain + n] = h[n];
    Pc[chain + n] = exp2f(S * a2[n]);
  }
}

// combine: per (chain,n), sequential over chunks; in-place Hc -> chunk-init states.
__global__ __launch_bounds__(256) void scomb_kernel(float* __restrict__ Hc,
    const float* __restrict__ Pc) {
  const size_t id = (size_t)blockIdx.x * 256 + threadIdx.x;   // 65536 threads
  const size_t stride = (size_t)NBATCH * DIN * NSTATE;
  float h = 0.f;
  for (int c = 0; c < CCH; c++) {
    size_t o = (size_t)c * stride + id;
    float hl = Hc[o], p = Pc[o];
    Hc[o] = h;
    h = fmaf(p, h, hl);
  }
}

// scan2 + fused causal dwconv + SiLU + gate:
// G = bf16((y_ssm + x*Dsk) * sigmoid(silu(conv(x)))), x = H (bf16).
__global__ __launch_bounds__(256) void scan2g_kernel(
    const unsigned short* __restrict__ DTBCb, const unsigned short* __restrict__ Hbf,
    const float* __restrict__ A_log, const float* __restrict__ Hinit,
    const float* __restrict__ cw, const float* __restrict__ cb,
    const float* __restrict__ dsk, unsigned short* __restrict__ G) {
  const int d = blockIdx.x * 256 + threadIdx.x;
  const int b = blockIdx.y, c = blockIdx.z;
  const size_t chain = ((size_t)c * (NBATCH * DIN) + (size_t)b * DIN + d) * 16;
  float a2[16], h[16];
#pragma unroll
  for (int n = 0; n < 16; n++) {
    a2[n] = -__expf(A_log[(size_t)d * NSTATE + n]) * LOG2E;
    h[n] = Hinit[chain + n];
  }
  __shared__ float sBC[TC][32];
  {
    int tt0 = threadIdx.x >> 2, cc = (threadIdx.x & 3) * 8;
    const size_t row = (size_t)(b * LSEQ + c * TC + tt0);
    us8 v = *(const us8*)(DTBCb + row * NCOL + DIN + cc);
#pragma unroll
    for (int j = 0; j < 8; j++) sBC[tt0][cc + j] = bf2f(v[j]);
  }
  __syncthreads();
  const float w0 = cw[d], w1 = cw[DIN + d], w2 = cw[2 * DIN + d], w3 = cw[3 * DIN + d];
  const float cbv = cb[d], dsv = dsk[d];
  const int t0 = c * TC;
  const size_t base = (size_t)b * LSEQ + t0;
  float xm1 = (t0 >= 1) ? bf2f(Hbf[(base - 1) * DIN + d]) : 0.f;
  float xm2 = (t0 >= 2) ? bf2f(Hbf[(base - 2) * DIN + d]) : 0.f;
  float xm3 = (t0 >= 3) ? bf2f(Hbf[(base - 3) * DIN + d]) : 0.f;
  for (int tt = 0; tt < TC; ++tt) {
    float sp = bf2f(DTBCb[(base + tt) * NCOL + d]);
    float x  = bf2f(Hbf[(base + tt) * DIN + d]);
    float sx = sp * x;
    float y0 = 0.f, y1 = 0.f, y2 = 0.f, y3 = 0.f;
#pragma unroll
    for (int n = 0; n < 16; n += 4) {
      h[n]     = fmaf(h[n],     exp2f(sp * a2[n]),     sx * sBC[tt][n]);
      h[n + 1] = fmaf(h[n + 1], exp2f(sp * a2[n + 1]), sx * sBC[tt][n + 1]);
      h[n + 2] = fmaf(h[n + 2], exp2f(sp * a2[n + 2]), sx * sBC[tt][n + 2]);
      h[n + 3] = fmaf(h[n + 3], exp2f(sp * a2[n + 3]), sx * sBC[tt][n + 3]);
      y0 = fmaf(h[n],     sBC[tt][16 + n],     y0);
      y1 = fmaf(h[n + 1], sBC[tt][16 + n + 1], y1);
      y2 = fmaf(h[n + 2], sBC[tt][16 + n + 2], y2);
      y3 = fmaf(h[n + 3], sBC[tt][16 + n + 3], y3);
    }
    float y = (y0 + y1) + (y2 + y3);
    float a = cbv + w0 * xm3 + w1 * xm2 + w2 * xm1 + w3 * x;   // causal conv K=4
    float sl = a * sigmoidf_(a);                               // silu
    float g = (y + x * dsv) * sigmoidf_(sl);                   // gate
    G[(base + tt) * DIN + d] = f2bf(g);
    xm3 = xm2; xm2 = xm1; xm1 = x;
  }
}

// ---------------- launch ----------------
extern "C" void kernel_launch(void* const* d_in, const int* in_sizes, int n_in,
                              void* d_out, int out_size, void* d_ws, size_t ws_size,
                              hipStream_t stream) {
  const float* x_in   = (const float*)d_in[0];
  const float* pos    = (const float*)d_in[1];
  const float* norm_w = (const float*)d_in[2];
  const float* norm_b = (const float*)d_in[3];
  const float* Win    = (const float*)d_in[4];
  const float* b_in   = (const float*)d_in[5];
  const float* A_log  = (const float*)d_in[6];
  const float* Wdt    = (const float*)d_in[7];
  const float* b_dt   = (const float*)d_in[8];
  const float* WB     = (const float*)d_in[9];
  const float* WC     = (const float*)d_in[10];
  const float* Dsk    = (const float*)d_in[11];
  const float* conv_w = (const float*)d_in[12];
  const float* conv_b = (const float*)d_in[13];
  const float* Wout   = (const float*)d_in[14];
  const float* b_out  = (const float*)d_in[15];
  const float* fnw    = (const float*)d_in[16];
  const float* fnb    = (const float*)d_in[17];

  uint8_t* ws = (uint8_t*)d_ws;
  constexpr size_t OFF_X      = 0;                      // [4096][1024] f32   16 MB
  constexpr size_t OFF_HBF    = 16777216;               // [4096][2048] bf16  16 MB
  constexpr size_t OFF_DTBC   = 33554432;               // [4096][2176] bf16  17 MB
  constexpr size_t OFF_XG     = 51380224;               // Xn bf16 / Gb bf16  16 MB
  constexpr size_t OFF_HC     = 68157440;               // 8 MB
  constexpr size_t OFF_PC     = 76546048;               // 8 MB
  constexpr size_t OFF_WINT   = 84934656;               // [2048][1024] bf16   4 MB
  constexpr size_t OFF_WDT    = 89128960;               // [2176][2048] bf16 ~8.5 MB
  constexpr size_t OFF_WOUT   = 98041856;               // [1024][2048] bf16   4 MB
  constexpr size_t OFF_BIAS2  = 102236160;              // [2176] f32
  constexpr size_t WS_NEEDED  = 102244864;
  if (ws_size < WS_NEEDED) return;

  float* X             = (float*)(ws + OFF_X);
  unsigned short* Hbf  = (unsigned short*)(ws + OFF_HBF);
  unsigned short* DTBCb= (unsigned short*)(ws + OFF_DTBC);
  unsigned short* Xn   = (unsigned short*)(ws + OFF_XG);
  unsigned short* Gb   = (unsigned short*)(ws + OFF_XG);
  float* Hc            = (float*)(ws + OFF_HC);
  float* Pc            = (float*)(ws + OFF_PC);
  unsigned short* WinT   = (unsigned short*)(ws + OFF_WINT);
  unsigned short* WdtBCT = (unsigned short*)(ws + OFF_WDT);
  unsigned short* WoutT  = (unsigned short*)(ws + OFF_WOUT);
  float* bias2         = (float*)(ws + OFF_BIAS2);

  for (int i = 0; i < 2; i++) {
    // ---- weight prep (bf16, transposed to [N][K]) ----
    tcvt_kernel<<<dim3(2048 / 64, 1024 / 64), 256, 0, stream>>>(
        Win + (size_t)i * D_MODEL * DIN, WinT, 1024, 2048);
    tcvt_kernel<<<dim3(2048 / 64, 2048 / 64), 256, 0, stream>>>(
        Wdt + (size_t)i * DIN * DIN, WdtBCT, 2048, 2048);
    wprep_kernel<<<361, 256, 0, stream>>>(
        WB + (size_t)i * DIN * NSTATE, WC + (size_t)i * DIN * NSTATE,
        b_dt + (size_t)i * DIN, WdtBCT, bias2);
    tcvt_kernel<<<dim3(1024 / 64, 2048 / 64), 256, 0, stream>>>(
        Wout + (size_t)i * DIN * D_MODEL, WoutT, 2048, 1024);

    // ---- layer compute ----
    if (i == 0)
      ln_kernel<<<4096, 256, 0, stream>>>(x_in, pos, norm_w, norm_b, Xn, nullptr, X);
    else
      ln_kernel<<<4096, 256, 0, stream>>>(X, nullptr, norm_w + D_MODEL,
                                          norm_b + D_MODEL, Xn, nullptr, nullptr);
    gemm_kernel<false, false, true><<<dim3(2048 / 128, 4096 / 128), 256, 0, stream>>>(
        Xn, WinT, b_in + (size_t)i * DIN, nullptr, nullptr, Hbf,
        NROWS, DIN, D_MODEL, 0);
    gemm_kernel<false, false, true><<<dim3(NCOL / 128, 4096 / 128), 256, 0, stream>>>(
        Hbf, WdtBCT, bias2, nullptr, nullptr, DTBCb, NROWS, NCOL, DIN, DIN);
    scan1_kernel<<<dim3(DIN / 256, NBATCH, CCH), 256, 0, stream>>>(
        DTBCb, Hbf, A_log + (size_t)i * DIN * NSTATE, Hc, Pc);
    scomb_kernel<<<(NBATCH * DIN * NSTATE) / 256, 256, 0, stream>>>(Hc, Pc);
    scan2g_kernel<<<dim3(DIN / 256, NBATCH, CCH), 256, 0, stream>>>(
        DTBCb, Hbf, A_log + (size_t)i * DIN * NSTATE, Hc,
        conv_w + (size_t)i * 4 * DIN, conv_b + (size_t)i * DIN,
        Dsk + (size_t)i * DIN, Gb);
    gemm_kernel<true, true, false><<<dim3(1024 / 128, 4096 / 128), 256, 0, stream>>>(
        Gb, WoutT, b_out + (size_t)i * D_MODEL, X, X, nullptr,
        NROWS, D_MODEL, DIN, 0);
  }

  ln_kernel<<<4096, 256, 0, stream>>>(X, nullptr, fnw, fnb, nullptr,
                                      (float*)d_out, nullptr);
}

// Round 5
// 649.985 us; speedup vs baseline: 1.1740x; 1.1740x over previous
//
#include <hip/hip_runtime.h>
#include <cstdint>
#include <cstddef>

#define D_MODEL 1024
#define DIN     2048
#define NSTATE  16
#define LSEQ    2048
#define NBATCH  2
#define NROWS   (NBATCH*LSEQ)   // 4096
#define NCOL    (DIN + 128)     // 2176 = sp(2048) | B(16) | C(16) | pad(96)
#define CCH     32              // scan chunks
#define TC      (LSEQ/CCH)      // 64 steps per chunk
#define LOG2E   1.4426950408889634f

typedef float  f32x4  __attribute__((ext_vector_type(4)));
typedef short  bf16x8 __attribute__((ext_vector_type(8)));
typedef unsigned short us8 __attribute__((ext_vector_type(8)));

__device__ __forceinline__ unsigned short f2bf(float f) {
  union { float f; unsigned u; } c; c.f = f;
  unsigned x = c.u + 0x7fffu + ((c.u >> 16) & 1u);   // RNE
  return (unsigned short)(x >> 16);
}
__device__ __forceinline__ float bf2f(unsigned short u) {
  union { unsigned u; float f; } c; c.u = (unsigned)u << 16; return c.f;
}
__device__ __forceinline__ float sigmoidf_(float x) { return 1.f / (1.f + __expf(-x)); }
__device__ __forceinline__ float softplusf_(float x) {
  return fmaxf(x, 0.f) + log1pf(__expf(-fabsf(x)));
}

// async global->LDS, 16B per lane; lds dest = wave-uniform base + lane*16
__device__ __forceinline__ void gll16(const void* g, void* l) {
  __builtin_amdgcn_global_load_lds(
      (const __attribute__((address_space(1))) void*)g,
      (__attribute__((address_space(3))) void*)l, 16, 0, 0);
}

// ---------------- layernorm (one row per block, D=1024); optional pos-add fuse --
__global__ __launch_bounds__(256) void ln_kernel(const float* __restrict__ Xin,
    const float* __restrict__ pos, const float* __restrict__ w,
    const float* __restrict__ b, unsigned short* __restrict__ outB,
    float* __restrict__ outF, float* __restrict__ Xsum) {
  int row = blockIdx.x, t = threadIdx.x;
  float4 v = *(const float4*)(Xin + (size_t)row * D_MODEL + t * 4);
  if (pos) {
    const float4 p = *(const float4*)(pos + (size_t)(row & (LSEQ - 1)) * D_MODEL + t * 4);
    v.x += p.x; v.y += p.y; v.z += p.z; v.w += p.w;
    if (Xsum) *(float4*)(Xsum + (size_t)row * D_MODEL + t * 4) = v;
  }
  float s  = v.x + v.y + v.z + v.w;
  float s2 = v.x * v.x + v.y * v.y + v.z * v.z + v.w * v.w;
#pragma unroll
  for (int o = 1; o < 64; o <<= 1) { s += __shfl_xor(s, o, 64); s2 += __shfl_xor(s2, o, 64); }
  __shared__ float ps[8];
  int wv = t >> 6;
  if ((t & 63) == 0) { ps[wv] = s; ps[wv + 4] = s2; }
  __syncthreads();
  s  = ps[0] + ps[1] + ps[2] + ps[3];
  s2 = ps[4] + ps[5] + ps[6] + ps[7];
  float mean = s * (1.f / D_MODEL);
  float var  = s2 * (1.f / D_MODEL) - mean * mean;
  float rs   = rsqrtf(var + 1e-5f);
  const float4 wv4 = *(const float4*)(w + t * 4);
  const float4 bv4 = *(const float4*)(b + t * 4);
  float o0 = (v.x - mean) * rs * wv4.x + bv4.x;
  float o1 = (v.y - mean) * rs * wv4.y + bv4.y;
  float o2 = (v.z - mean) * rs * wv4.z + bv4.z;
  float o3 = (v.w - mean) * rs * wv4.w + bv4.w;
  if (outB) {
    ushort4 o; o.x = f2bf(o0); o.y = f2bf(o1); o.z = f2bf(o2); o.w = f2bf(o3);
    *(ushort4*)(outB + (size_t)row * D_MODEL + t * 4) = o;
  } else {
    float4 o; o.x = o0; o.y = o1; o.z = o2; o.w = o3;
    *(float4*)(outF + (size_t)row * D_MODEL + t * 4) = o;
  }
}

// ---------------- transpose + fp32->bf16: out[n][k] = in[k][n] ----------------
__global__ __launch_bounds__(256) void tcvt_kernel(const float* __restrict__ in,
    unsigned short* __restrict__ out, int K_, int N_) {
  __shared__ float tile[64][68];
  int n0 = blockIdx.x * 64, k0 = blockIdx.y * 64;
  int t = threadIdx.x;
  int r = t >> 4, cc = (t & 15) * 4;
#pragma unroll
  for (int j = 0; j < 4; j++) {
    const float4 v = *(const float4*)(in + (size_t)(k0 + r + j * 16) * N_ + n0 + cc);
    tile[r + j * 16][cc + 0] = v.x; tile[r + j * 16][cc + 1] = v.y;
    tile[r + j * 16][cc + 2] = v.z; tile[r + j * 16][cc + 3] = v.w;
  }
  __syncthreads();
  int nr = t >> 2, kc = (t & 3) * 16;
  unsigned u[8];
#pragma unroll
  for (int i = 0; i < 8; i++) {
    unsigned lo = f2bf(tile[kc + 2 * i][nr]);
    unsigned hi = f2bf(tile[kc + 2 * i + 1][nr]);
    u[i] = lo | (hi << 16);
  }
  uint4* dst = (uint4*)(out + (size_t)(n0 + nr) * K_ + k0 + kc);
  uint4 w0; w0.x = u[0]; w0.y = u[1]; w0.z = u[2]; w0.w = u[3];
  uint4 w1; w1.x = u[4]; w1.y = u[5]; w1.z = u[6]; w1.w = u[7];
  dst[0] = w0; dst[1] = w1;
}

// ---- merged prep: WB/WC^T rows 2048..2079, zero pad rows 2080..2175, bias2 ----
__global__ __launch_bounds__(256) void wprep_kernel(const float* __restrict__ WB,
    const float* __restrict__ WC, const float* __restrict__ b_dt,
    unsigned short* __restrict__ Wt, float* __restrict__ bias2) {
  int id = blockIdx.x * 256 + threadIdx.x;
  if (id < 65536) {                                     // 32 x 2048 transpose fill
    int k = id & (DIN - 1);
    int n2 = id >> 11;
    float v = (n2 < NSTATE) ? WB[(size_t)k * NSTATE + n2]
                            : WC[(size_t)k * NSTATE + (n2 - NSTATE)];
    Wt[(size_t)(DIN + n2) * DIN + k] = f2bf(v);
  } else if (id < 90112) {                              // zero 96x2048 bf16, x8 vec
    int z = id - 65536;
    uint4 zz; zz.x = zz.y = zz.z = zz.w = 0u;
    *(uint4*)(Wt + (size_t)2080 * DIN + (size_t)z * 8) = zz;
  } else if (id < 90112 + NCOL) {                       // bias2
    int i = id - 90112;
    bias2[i] = (i < DIN) ? b_dt[i] : 0.f;
  }
}

// ---------------- bf16 MFMA GEMM: out = A[M][K] @ Bt[N][K]^T + bias (+res) ----
// Tile (4*MW) x 64, BK=32. 4 waves, wave w owns rows [w*MW, (w+1)*MW) x all 64 cols.
// Simple 2-barrier loop (proven m97-class), global_load_lds staging, XCD swizzle.
// MW=32: 128x64 tile; MW=16: 64x64 tile (more blocks for small-N GEMMs).
template <int MW, bool HAS_RES, bool WRITE_F32, bool WRITE_BF>
__global__ __launch_bounds__(256) void gemm_kernel(
    const unsigned short* __restrict__ A, const unsigned short* __restrict__ Bt,
    const float* __restrict__ bias, const float* res,
    float* outF, unsigned short* __restrict__ outB,
    int M, int N, int K, int spCols) {
  constexpr int TM = MW * 4;
  constexpr int MF = MW / 16;                          // A frags per wave
  __shared__ unsigned short sA[TM * 32];
  __shared__ unsigned short sB[64 * 32];
  const int t = threadIdx.x;
  const int lane = t & 63, wave = t >> 6;

  // XCD-chunked bijective swizzle (m204)
  const int gx = gridDim.x;
  const int orig = blockIdx.y * gx + blockIdx.x;
  const int nwg = gx * gridDim.y;
  const int q = nwg >> 3, r = nwg & 7;
  const int xcd = orig & 7, pp = orig >> 3;
  const int wgid = (xcd < r) ? (xcd * (q + 1) + pp)
                             : (r * (q + 1) + (xcd - r) * q + pp);
  const int mt = wgid / gx, nt = wgid - mt * gx;
  const int m0 = mt * TM, n0 = nt * 64;

  const int ar = t >> 2, ac = (t & 3) * 8;             // staging: 16B/lane, linear
  const int wseg = wave * 16 * 32;                     // wave-uniform LDS base (elems)
  const int lr = lane & 15, lk = (lane >> 4) * 8;

  f32x4 acc[MF][4];
#pragma unroll
  for (int m = 0; m < MF; m++)
#pragma unroll
    for (int n = 0; n < 4; n++) acc[m][n] = (f32x4)0.f;

  for (int k0 = 0; k0 < K; k0 += 32) {
    __syncthreads();                                    // prev tile fully consumed
    gll16(A + (size_t)(m0 + ar) * K + k0 + ac, sA + wseg);
    if (MW == 32)
      gll16(A + (size_t)(m0 + 64 + ar) * K + k0 + ac, sA + 64 * 32 + wseg);
    gll16(Bt + (size_t)(n0 + ar) * K + k0 + ac, sB + wseg);
    __syncthreads();                                    // drains vmcnt -> tile ready
    bf16x8 af[MF], bg[4];
#pragma unroll
    for (int m = 0; m < MF; m++)
      af[m] = *(const bf16x8*)(sA + (wave * MW + m * 16 + lr) * 32 + lk);
#pragma unroll
    for (int n = 0; n < 4; n++)
      bg[n] = *(const bf16x8*)(sB + (n * 16 + lr) * 32 + lk);
#pragma unroll
    for (int m = 0; m < MF; m++)
#pragma unroll
      for (int n = 0; n < 4; n++)
        acc[m][n] = __builtin_amdgcn_mfma_f32_16x16x32_bf16(af[m], bg[n], acc[m][n], 0, 0, 0);
  }

  const int lq = lane >> 4;
#pragma unroll
  for (int m = 0; m < MF; m++) {
    int row = m0 + wave * MW + m * 16 + lq * 4;
#pragma unroll
    for (int n = 0; n < 4; n++) {
      int col = n0 + n * 16 + lr;
      float bv = bias[col];
      bool sp = col < spCols;
#pragma unroll
      for (int j = 0; j < 4; j++) {
        size_t idx = (size_t)(row + j) * N + col;
        float v = acc[m][n][j] + bv;
        if (HAS_RES) v += res[idx];
        if (sp) v = softplusf_(v);
        if (WRITE_F32) outF[idx] = v;
        if (WRITE_BF) outB[idx] = f2bf(v);
      }
    }
  }
}

// ---------------- chunked selective scan (bf16 inputs) ----------------
// Thread owns one channel d and all 16 states in registers. grid (DIN/256, B, CCH).
// DTBCb: [B*L][NCOL] bf16, cols [0,2048)=softplus(dt), [2048,2064)=B, [2064,2080)=C.
__global__ __launch_bounds__(256) void scan1_kernel(
    const unsigned short* __restrict__ DTBCb, const unsigned short* __restrict__ Hbf,
    const float* __restrict__ A_log, float* __restrict__ Hc, float* __restrict__ Pc) {
  const int d = blockIdx.x * 256 + threadIdx.x;
  const int b = blockIdx.y, c = blockIdx.z;
  float a2[16], h[16];
#pragma unroll
  for (int n = 0; n < 16; n++) {
    a2[n] = -__expf(A_log[(size_t)d * NSTATE + n]) * LOG2E;
    h[n] = 0.f;
  }
  __shared__ float sBC[TC][32];                         // B | C per step
  {
    int tt0 = threadIdx.x >> 2, cc = (threadIdx.x & 3) * 8;
    const size_t row = (size_t)(b * LSEQ + c * TC + tt0);
    us8 v = *(const us8*)(DTBCb + row * NCOL + DIN + cc);
#pragma unroll
    for (int j = 0; j < 8; j++) sBC[tt0][cc + j] = bf2f(v[j]);
  }
  __syncthreads();
  float S = 0.f;
  const size_t base = (size_t)(b * LSEQ + c * TC);
  for (int tt = 0; tt < TC; ++tt) {
    float sp = bf2f(DTBCb[(base + tt) * NCOL + d]);
    float x  = bf2f(Hbf[(base + tt) * DIN + d]);
    S += sp;
    float sx = sp * x;
#pragma unroll
    for (int n = 0; n < 16; n++)
      h[n] = fmaf(h[n], exp2f(sp * a2[n]), sx * sBC[tt][n]);
  }
  const size_t chain = ((size_t)c * (NBATCH * DIN) + (size_t)b * DIN + d) * 16;
#pragma unroll
  for (int n = 0; n < 16; n++) {
    Hc[chain + n] = h[n];
    Pc[chain + n] = exp2f(S * a2[n]);
  }
}

// combine: per (chain,n), sequential over chunks; in-place Hc -> chunk-init states.
__global__ __launch_bounds__(256) void scomb_kernel(float* __restrict__ Hc,
    const float* __restrict__ Pc) {
  const size_t id = (size_t)blockIdx.x * 256 + threadIdx.x;   // 65536 threads
  const size_t stride = (size_t)NBATCH * DIN * NSTATE;
  float h = 0.f;
  for (int c = 0; c < CCH; c++) {
    size_t o = (size_t)c * stride + id;
    float hl = Hc[o], p = Pc[o];
    Hc[o] = h;
    h = fmaf(p, h, hl);
  }
}

// scan2 + fused causal dwconv + SiLU + gate:
// G = bf16((y_ssm + x*Dsk) * sigmoid(silu(conv(x)))), x = H (bf16).
__global__ __launch_bounds__(256) void scan2g_kernel(
    const unsigned short* __restrict__ DTBCb, const unsigned short* __restrict__ Hbf,
    const float* __restrict__ A_log, const float* __restrict__ Hinit,
    const float* __restrict__ cw, const float* __restrict__ cb,
    const float* __restrict__ dsk, unsigned short* __restrict__ G) {
  const int d = blockIdx.x * 256 + threadIdx.x;
  const int b = blockIdx.y, c = blockIdx.z;
  const size_t chain = ((size_t)c * (NBATCH * DIN) + (size_t)b * DIN + d) * 16;
  float a2[16], h[16];
#pragma unroll
  for (int n = 0; n < 16; n++) {
    a2[n] = -__expf(A_log[(size_t)d * NSTATE + n]) * LOG2E;
    h[n] = Hinit[chain + n];
  }
  __shared__ float sBC[TC][32];
  {
    int tt0 = threadIdx.x >> 2, cc = (threadIdx.x & 3) * 8;
    const size_t row = (size_t)(b * LSEQ + c * TC + tt0);
    us8 v = *(const us8*)(DTBCb + row * NCOL + DIN + cc);
#pragma unroll
    for (int j = 0; j < 8; j++) sBC[tt0][cc + j] = bf2f(v[j]);
  }
  __syncthreads();
  const float w0 = cw[d], w1 = cw[DIN + d], w2 = cw[2 * DIN + d], w3 = cw[3 * DIN + d];
  const float cbv = cb[d], dsv = dsk[d];
  const int t0 = c * TC;
  const size_t base = (size_t)b * LSEQ + t0;
  float xm1 = (t0 >= 1) ? bf2f(Hbf[(base - 1) * DIN + d]) : 0.f;
  float xm2 = (t0 >= 2) ? bf2f(Hbf[(base - 2) * DIN + d]) : 0.f;
  float xm3 = (t0 >= 3) ? bf2f(Hbf[(base - 3) * DIN + d]) : 0.f;
  for (int tt = 0; tt < TC; ++tt) {
    float sp = bf2f(DTBCb[(base + tt) * NCOL + d]);
    float x  = bf2f(Hbf[(base + tt) * DIN + d]);
    float sx = sp * x;
    float y0 = 0.f, y1 = 0.f, y2 = 0.f, y3 = 0.f;
#pragma unroll
    for (int n = 0; n < 16; n += 4) {
      h[n]     = fmaf(h[n],     exp2f(sp * a2[n]),     sx * sBC[tt][n]);
      h[n + 1] = fmaf(h[n + 1], exp2f(sp * a2[n + 1]), sx * sBC[tt][n + 1]);
      h[n + 2] = fmaf(h[n + 2], exp2f(sp * a2[n + 2]), sx * sBC[tt][n + 2]);
      h[n + 3] = fmaf(h[n + 3], exp2f(sp * a2[n + 3]), sx * sBC[tt][n + 3]);
      y0 = fmaf(h[n],     sBC[tt][16 + n],     y0);
      y1 = fmaf(h[n + 1], sBC[tt][16 + n + 1], y1);
      y2 = fmaf(h[n + 2], sBC[tt][16 + n + 2], y2);
      y3 = fmaf(h[n + 3], sBC[tt][16 + n + 3], y3);
    }
    float y = (y0 + y1) + (y2 + y3);
    float a = cbv + w0 * xm3 + w1 * xm2 + w2 * xm1 + w3 * x;   // causal conv K=4
    float sl = a * sigmoidf_(a);                               // silu
    float g = (y + x * dsv) * sigmoidf_(sl);                   // gate
    G[(base + tt) * DIN + d] = f2bf(g);
    xm3 = xm2; xm2 = xm1; xm1 = x;
  }
}

// ---------------- launch ----------------
extern "C" void kernel_launch(void* const* d_in, const int* in_sizes, int n_in,
                              void* d_out, int out_size, void* d_ws, size_t ws_size,
                              hipStream_t stream) {
  const float* x_in   = (const float*)d_in[0];
  const float* pos    = (const float*)d_in[1];
  const float* norm_w = (const float*)d_in[2];
  const float* norm_b = (const float*)d_in[3];
  const float* Win    = (const float*)d_in[4];
  const float* b_in   = (const float*)d_in[5];
  const float* A_log  = (const float*)d_in[6];
  const float* Wdt    = (const float*)d_in[7];
  const float* b_dt   = (const float*)d_in[8];
  const float* WB     = (const float*)d_in[9];
  const float* WC     = (const float*)d_in[10];
  const float* Dsk    = (const float*)d_in[11];
  const float* conv_w = (const float*)d_in[12];
  const float* conv_b = (const float*)d_in[13];
  const float* Wout   = (const float*)d_in[14];
  const float* b_out  = (const float*)d_in[15];
  const float* fnw    = (const float*)d_in[16];
  const float* fnb    = (const float*)d_in[17];

  uint8_t* ws = (uint8_t*)d_ws;
  constexpr size_t OFF_X      = 0;                      // [4096][1024] f32   16 MB
  constexpr size_t OFF_HBF    = 16777216;               // [4096][2048] bf16  16 MB
  constexpr size_t OFF_DTBC   = 33554432;               // [4096][2176] bf16  17 MB
  constexpr size_t OFF_XG     = 51380224;               // Xn bf16 / Gb bf16  16 MB
  constexpr size_t OFF_HC     = 68157440;               // 8 MB
  constexpr size_t OFF_PC     = 76546048;               // 8 MB
  constexpr size_t OFF_WINT   = 84934656;               // [2048][1024] bf16   4 MB
  constexpr size_t OFF_WDT    = 89128960;               // [2176][2048] bf16 ~8.5 MB
  constexpr size_t OFF_WOUT   = 98041856;               // [1024][2048] bf16   4 MB
  constexpr size_t OFF_BIAS2  = 102236160;              // [2176] f32
  constexpr size_t WS_NEEDED  = 102244864;
  if (ws_size < WS_NEEDED) return;

  float* X             = (float*)(ws + OFF_X);
  unsigned short* Hbf  = (unsigned short*)(ws + OFF_HBF);
  unsigned short* DTBCb= (unsigned short*)(ws + OFF_DTBC);
  unsigned short* Xn   = (unsigned short*)(ws + OFF_XG);
  unsigned short* Gb   = (unsigned short*)(ws + OFF_XG);
  float* Hc            = (float*)(ws + OFF_HC);
  float* Pc            = (float*)(ws + OFF_PC);
  unsigned short* WinT   = (unsigned short*)(ws + OFF_WINT);
  unsigned short* WdtBCT = (unsigned short*)(ws + OFF_WDT);
  unsigned short* WoutT  = (unsigned short*)(ws + OFF_WOUT);
  float* bias2         = (float*)(ws + OFF_BIAS2);

  for (int i = 0; i < 2; i++) {
    // ---- weight prep (bf16, transposed to [N][K]) ----
    tcvt_kernel<<<dim3(2048 / 64, 1024 / 64), 256, 0, stream>>>(
        Win + (size_t)i * D_MODEL * DIN, WinT, 1024, 2048);
    tcvt_kernel<<<dim3(2048 / 64, 2048 / 64), 256, 0, stream>>>(
        Wdt + (size_t)i * DIN * DIN, WdtBCT, 2048, 2048);
    wprep_kernel<<<361, 256, 0, stream>>>(
        WB + (size_t)i * DIN * NSTATE, WC + (size_t)i * DIN * NSTATE,
        b_dt + (size_t)i * DIN, WdtBCT, bias2);
    tcvt_kernel<<<dim3(1024 / 64, 2048 / 64), 256, 0, stream>>>(
        Wout + (size_t)i * DIN * D_MODEL, WoutT, 2048, 1024);

    // ---- layer compute ----
    if (i == 0)
      ln_kernel<<<4096, 256, 0, stream>>>(x_in, pos, norm_w, norm_b, Xn, nullptr, X);
    else
      ln_kernel<<<4096, 256, 0, stream>>>(X, nullptr, norm_w + D_MODEL,
                                          norm_b + D_MODEL, Xn, nullptr, nullptr);
    // Win: M=4096 N=2048 K=1024, 128x64 tile -> 32x32 = 1024 blocks (4/CU)
    gemm_kernel<32, false, false, true><<<dim3(2048 / 64, 4096 / 128), 256, 0, stream>>>(
        Xn, WinT, b_in + (size_t)i * DIN, nullptr, nullptr, Hbf,
        NROWS, DIN, D_MODEL, 0);
    // dt: M=4096 N=2176 K=2048, 128x64 tile -> 34x32 = 1088 blocks (4.25/CU)
    gemm_kernel<32, false, false, true><<<dim3(NCOL / 64, 4096 / 128), 256, 0, stream>>>(
        Hbf, WdtBCT, bias2, nullptr, nullptr, DTBCb, NROWS, NCOL, DIN, DIN);
    scan1_kernel<<<dim3(DIN / 256, NBATCH, CCH), 256, 0, stream>>>(
        DTBCb, Hbf, A_log + (size_t)i * DIN * NSTATE, Hc, Pc);
    scomb_kernel<<<(NBATCH * DIN * NSTATE) / 256, 256, 0, stream>>>(Hc, Pc);
    scan2g_kernel<<<dim3(DIN / 256, NBATCH, CCH), 256, 0, stream>>>(
        DTBCb, Hbf, A_log + (size_t)i * DIN * NSTATE, Hc,
        conv_w + (size_t)i * 4 * DIN, conv_b + (size_t)i * DIN,
        Dsk + (size_t)i * DIN, Gb);
    // Wout: M=4096 N=1024 K=2048, 64x64 tile -> 16x64 = 1024 blocks (4/CU)
    gemm_kernel<16, true, true, false><<<dim3(1024 / 64, 4096 / 64), 256, 0, stream>>>(
        Gb, WoutT, b_out + (size_t)i * D_MODEL, X, X, nullptr,
        NROWS, D_MODEL, DIN, 0);
  }

  ln_kernel<<<4096, 256, 0, stream>>>(X, nullptr, fnw, fnb, nullptr,
                                      (float*)d_out, nullptr);
}